// Round 7
// baseline (76.621 us; speedup 1.0000x reference)
//
#include <hip/hip_runtime.h>

#define B_DIM 256
#define E_DIM 8192
#define C_DIM 19
#define XBLK  32   // E_DIM / B_DIM

// ws layout (floats), all plain writes (no atomics, no pre-zero needed):
//  [0    .. 607 ]  capP[c*32+x]  partial count of (e_true>=0.5) over j-slice
//  [608  .. 626 ]  n_pos[c]      count of (y_true>=0.5) over B
//  [627  .. 645 ]  sum_yp[c]     sum of y_pred over B
//  [646  .. 1253]  mP[c*32+x]    partial weighted pair sum
#define WS_CAP  0
#define WS_NPOS 608
#define WS_SYP  627
#define WS_M    646

// Block-wide sum (256 threads = 4 waves). Result valid on tid==0 only.
__device__ __forceinline__ float block_sum(float v, int tid, float* red4) {
    #pragma unroll
    for (int off = 32; off > 0; off >>= 1) v += __shfl_down(v, off, 64);
    if ((tid & 63) == 0) red4[tid >> 6] = v;
    __syncthreads();
    float r = 0.0f;
    if (tid == 0) r = red4[0] + red4[1] + red4[2] + red4[3];
    __syncthreads();
    return r;
}

// K1: grid (32,19) x 256. Cap partials + L2 prefetch of k2's cold arrays.
// The (ep+rp+rn)*0.0f term is numerically +0.0 (finite inputs) so cs is
// bitwise unchanged, but it forces the three loads -> warms the XCD L2 that
// k2's identically-shaped grid will hit (same dispatch round-robin).
__global__ void __launch_bounds__(B_DIM)
rocstar_k1(const float* __restrict__ y_pred,
           const float* __restrict__ y_true,
           const float* __restrict__ epoch_pred,
           const float* __restrict__ epoch_true,
           const float* __restrict__ rand_pos,
           const float* __restrict__ rand_neg,
           float* __restrict__ ws) {
    const int c    = blockIdx.y;
    const int x    = blockIdx.x;
    const int tid  = threadIdx.x;
    const int base = (x * B_DIM + tid) * C_DIM + c;
    __shared__ float red4[4];

    const float pf  = (epoch_pred[base] + rand_pos[base] + rand_neg[base]) * 0.0f;
    const float cnt = ((epoch_true[base] >= 0.5f) ? 1.0f : 0.0f) + pf;
    const float cs  = block_sum(cnt, tid, red4);
    if (tid == 0) ws[WS_CAP + c * XBLK + x] = cs;

    if (x == 0) {
        const float ypv = y_pred[tid * C_DIM + c];
        const float ytv = (y_true[tid * C_DIM + c] >= 0.5f) ? 1.0f : 0.0f;
        const float np  = block_sum(ytv, tid, red4);
        if (tid == 0) ws[WS_NPOS + c] = np;
        const float sy  = block_sum(ypv, tid, red4);
        if (tid == 0) ws[WS_SYP + c] = sy;
    }
}

// K2: grid (32,19) x 256. Double-compacted pair sums (R6 structure):
//  j-axis: ballot-compact the ~p*256 active j's into s_act.
//  i-axis: pos/neg yp lists with relu-killed sentinels.
// cap fold is now 1 load/lane + wave shuffle reduce (was 32 uniform loads).
__global__ void __launch_bounds__(B_DIM)
rocstar_k2(const float* __restrict__ y_pred,
           const float* __restrict__ y_true,
           const float* __restrict__ epoch_pred,
           const float* __restrict__ epoch_true,
           const float* __restrict__ gamma,
           const float* __restrict__ rand_pos,
           const float* __restrict__ rand_neg,
           float* __restrict__ ws) {
    const int c   = blockIdx.y;
    const int x   = blockIdx.x;
    const int tid = threadIdx.x;
    const int j   = x * B_DIM + tid;
    const int wv  = tid >> 6;
    const int ln  = tid & 63;

    __shared__ __align__(8) float s_pos[B_DIM];  // yp where pm=1, pad +1e30
    __shared__ __align__(8) float s_neg[B_DIM];  // yp where pm=0, pad -1e30
    __shared__ float2 s_act[B_DIM];              // {a, s} of active j's
    __shared__ int    s_pcnt[4], s_acnt[4];
    __shared__ float  red4[4];

    // ---- per-thread loads (L2-warm thanks to k1's prefetch) ----
    const float yp  = y_pred[tid * C_DIM + c];
    const bool  pmb = (y_true[tid * C_DIM + c] >= 0.5f);

    // cap: lanes 0..31 load one partial each, wave-reduce, broadcast
    float cv = (ln < XBLK) ? ws[WS_CAP + c * XBLK + ln] : 0.0f;
    #pragma unroll
    for (int off = 16; off > 0; off >>= 1) cv += __shfl_down(cv, off, 64);
    const float cap = __shfl(cv, 0, 64);
    const float p   = 1000.0f / fmaxf(cap, 1.0f); // MAX_POS / cap_pos (f32, as ref)
    const float g   = gamma[c];

    const float ep = epoch_pred[j * C_DIM + c];
    const bool  et = epoch_true[j * C_DIM + c] >= 0.5f;
    const float rp = rand_pos[j * C_DIM + c];
    const float rn = rand_neg[j * C_DIM + c];

    // faithful to the reference "bug": both masks use p from cap_pos
    const bool  act = (et ? rp : rn) < p;
    // et=0 (epoch neg, m2): d = (ep - yp) + g vs pm=1 rows -> s = +1
    // et=1 (epoch pos, m3): d = (yp - ep) + g vs pm=0 rows -> s = -1
    const float s = et ? -1.0f : 1.0f;
    const float a = fmaf(s, ep, g);               // s*ep + g

    // ---- ballots & per-wave counts ----
    const unsigned long long pmask = __ballot(pmb);
    const unsigned long long amask = __ballot(act);
    if (ln == 0) { s_pcnt[wv] = __popcll(pmask); s_acnt[wv] = __popcll(amask); }
    __syncthreads();

    int posBase = 0, actBase = 0, np = 0, total = 0;
    #pragma unroll
    for (int wk = 0; wk < 4; ++wk) {
        const int pc = s_pcnt[wk], ac = s_acnt[wk];
        np    += pc;
        total += ac;
        if (wk < wv) { posBase += pc; actBase += ac; }
    }
    const int negBase = (wv << 6) - posBase;      // 64*wv - pos_prefix
    const unsigned long long lt = (1ull << ln) - 1ull;
    const int prank = __popcll(pmask & lt);
    const int arank = __popcll(amask & lt);

    // ---- scatter compacted data ----
    if (pmb) s_pos[posBase + prank]        = yp;
    else     s_neg[negBase + (ln - prank)] = yp;
    if (act) s_act[actBase + arank] = make_float2(a, s);

    // ---- sentinel pads (relu kills them) ----
    const int nn   = B_DIM - np;
    const int mx   = (np > nn) ? np : nn;
    const int trip = (mx + 1) >> 1;
    const int lim  = trip << 1;                   // <= 256
    if (tid >= np && tid < lim) s_pos[tid] =  1.0e30f;
    if (tid >= nn && tid < lim) s_neg[tid] = -1.0e30f;
    __syncthreads();

    // ---- compacted inner loop (~62 of 256 threads, ~68 f2 iters) ----
    float acc0 = 0.0f, acc1 = 0.0f;
    if (tid < total) {
        const float2 as   = s_act[tid];
        const float  nsgn = -as.y;
        const float2* lst = (as.y > 0.0f) ? (const float2*)s_pos
                                          : (const float2*)s_neg;
        #pragma unroll 4
        for (int k = 0; k < trip; ++k) {
            const float2 v = lst[k];              // 2-address broadcast: free
            float d0 = fmaxf(fmaf(nsgn, v.x, as.x), 0.0f);
            acc0 = fmaf(d0, d0, acc0);
            float d1 = fmaxf(fmaf(nsgn, v.y, as.x), 0.0f);
            acc1 = fmaf(d1, d1, acc1);
        }
    }

    const float bs = block_sum(acc0 + acc1, tid, red4);
    if (tid == 0) ws[WS_M + c * XBLK + x] = bs;
}

// K3: one block. Thread c<19 folds its class's 32 partials + degenerate logic;
// single-wave shuffle reduce over classes.
__global__ void rocstar_k3(const float* __restrict__ ws,
                           float* __restrict__ out) {
    const int tid = threadIdx.x;
    float r = 0.0f;
    if (tid < C_DIM) {
        float m = 0.0f;
        #pragma unroll
        for (int t = 0; t < XBLK; ++t) m += ws[WS_M + tid * XBLK + t];
        float v = m / 1000.0f;                  // m2/MAX_POS + m3/MAX_NEG
        if (isnan(v)) v = 0.0f;
        const float npos = ws[WS_NPOS + tid];
        r = (npos == 0.0f || npos == (float)B_DIM)
                ? ws[WS_SYP + tid] * 1e-8f      // degenerate: sum(yp)*1e-8
                : v;
    }
    #pragma unroll
    for (int off = 16; off > 0; off >>= 1) r += __shfl_down(r, off, 64);
    if (tid == 0) out[0] = r / (float)C_DIM;    // mean over classes
}

extern "C" void kernel_launch(void* const* d_in, const int* in_sizes, int n_in,
                              void* d_out, int out_size, void* d_ws, size_t ws_size,
                              hipStream_t stream) {
    const float* y_pred     = (const float*)d_in[0];
    const float* y_true     = (const float*)d_in[1];
    const float* epoch_pred = (const float*)d_in[2];
    const float* epoch_true = (const float*)d_in[3];
    const float* gamma      = (const float*)d_in[4];
    const float* rand_pos   = (const float*)d_in[5];
    const float* rand_neg   = (const float*)d_in[6];
    float*       out        = (float*)d_out;
    float*       ws         = (float*)d_ws;

    const dim3 grid(XBLK, C_DIM);   // 32 x 19
    rocstar_k1<<<grid, B_DIM, 0, stream>>>(y_pred, y_true, epoch_pred, epoch_true,
                                           rand_pos, rand_neg, ws);
    rocstar_k2<<<grid, B_DIM, 0, stream>>>(y_pred, y_true, epoch_pred, epoch_true,
                                           gamma, rand_pos, rand_neg, ws);
    rocstar_k3<<<1, 64, 0, stream>>>(ws, out);
}

// Round 8
// 74.782 us; speedup vs baseline: 1.0246x; 1.0246x over previous
//
#include <hip/hip_runtime.h>

#define B_DIM 256
#define E_DIM 8192
#define C_DIM 19
#define XBLK  32   // E_DIM / B_DIM

// ws layout (floats), all plain writes (no atomics, no pre-zero needed):
//  [0    .. 607 ]  capP[c*32+x]  partial count of (e_true>=0.5) over j-slice
//  [608  .. 626 ]  n_pos[c]      count of (y_true>=0.5) over B
//  [627  .. 645 ]  sum_yp[c]     sum of y_pred over B
//  [646  .. 1253]  mP[c*32+x]    partial weighted pair sum
#define WS_CAP  0
#define WS_NPOS 608
#define WS_SYP  627
#define WS_M    646

// Block-wide sum (256 threads = 4 waves). Result valid on tid==0 only.
__device__ __forceinline__ float block_sum(float v, int tid, float* red4) {
    #pragma unroll
    for (int off = 32; off > 0; off >>= 1) v += __shfl_down(v, off, 64);
    if ((tid & 63) == 0) red4[tid >> 6] = v;
    __syncthreads();
    float r = 0.0f;
    if (tid == 0) r = red4[0] + red4[1] + red4[2] + red4[3];
    __syncthreads();
    return r;
}

// K1: grid (32,19) x 256. Per-class partial cap counts; block x==0 also does
// the B-reductions (n_pos, sum_yp). Plain writes; kernel boundary publishes.
// NOTE (R7 lesson): no prefetch of k2's arrays — harness input-restore leaves
// all inputs L2-warm already; prefetch only lengthens k1's critical path.
__global__ void __launch_bounds__(B_DIM)
rocstar_k1(const float* __restrict__ y_pred,
           const float* __restrict__ y_true,
           const float* __restrict__ epoch_true,
           float* __restrict__ ws) {
    const int c   = blockIdx.y;
    const int x   = blockIdx.x;
    const int tid = threadIdx.x;
    const int j   = x * B_DIM + tid;
    __shared__ float red4[4];

    const float cnt = (epoch_true[j * C_DIM + c] >= 0.5f) ? 1.0f : 0.0f;
    const float cs  = block_sum(cnt, tid, red4);
    if (tid == 0) ws[WS_CAP + c * XBLK + x] = cs;

    if (x == 0) {
        const float ypv = y_pred[tid * C_DIM + c];
        const float ytv = (y_true[tid * C_DIM + c] >= 0.5f) ? 1.0f : 0.0f;
        const float np  = block_sum(ytv, tid, red4);
        if (tid == 0) ws[WS_NPOS + c] = np;
        const float sy  = block_sum(ypv, tid, red4);
        if (tid == 0) ws[WS_SYP + c] = sy;
    }
}

// K2: grid (32,19) x 256. Double-compacted pair sums (measured-best R6 form):
//  j-axis: only ~p*256 threads have w!=0 -> ballot-compact {a,s} into s_act.
//  i-axis: s=+1 (epoch neg) needs pm=1 rows only; s=-1 needs pm=0 rows only ->
//          compact yp into pos/neg lists, sentinel-padded so the relu kills pads.
// Inner loop: 3 VALU/element over ~max(np,nn) elements, ~one active wave.
__global__ void __launch_bounds__(B_DIM)
rocstar_k2(const float* __restrict__ y_pred,
           const float* __restrict__ y_true,
           const float* __restrict__ epoch_pred,
           const float* __restrict__ epoch_true,
           const float* __restrict__ gamma,
           const float* __restrict__ rand_pos,
           const float* __restrict__ rand_neg,
           float* __restrict__ ws) {
    const int c   = blockIdx.y;
    const int x   = blockIdx.x;
    const int tid = threadIdx.x;
    const int j   = x * B_DIM + tid;
    const int wv  = tid >> 6;
    const int ln  = tid & 63;

    __shared__ __align__(8) float s_pos[B_DIM];  // yp where pm=1, pad +1e30
    __shared__ __align__(8) float s_neg[B_DIM];  // yp where pm=0, pad -1e30
    __shared__ float2 s_act[B_DIM];              // {a, s} of active j's
    __shared__ int    s_pcnt[4], s_acnt[4];
    __shared__ float  red4[4];

    // ---- per-thread loads (L2-warm via harness input restore) ----
    const float yp  = y_pred[tid * C_DIM + c];
    const bool  pmb = (y_true[tid * C_DIM + c] >= 0.5f);

    float cap = 0.0f;
    #pragma unroll
    for (int t = 0; t < XBLK; ++t) cap += ws[WS_CAP + c * XBLK + t];
    const float p = 1000.0f / fmaxf(cap, 1.0f);   // MAX_POS / cap_pos (f32, as ref)
    const float g = gamma[c];

    const float ep = epoch_pred[j * C_DIM + c];
    const bool  et = epoch_true[j * C_DIM + c] >= 0.5f;
    const float rp = rand_pos[j * C_DIM + c];
    const float rn = rand_neg[j * C_DIM + c];

    // faithful to the reference "bug": both masks use p from cap_pos
    const bool  act = (et ? rp : rn) < p;
    // et=0 (epoch neg, m2): d = (ep - yp) + g vs pm=1 rows -> s = +1
    // et=1 (epoch pos, m3): d = (yp - ep) + g vs pm=0 rows -> s = -1
    const float s = et ? -1.0f : 1.0f;
    const float a = fmaf(s, ep, g);               // s*ep + g

    // ---- ballots & per-wave counts ----
    const unsigned long long pmask = __ballot(pmb);
    const unsigned long long amask = __ballot(act);
    if (ln == 0) { s_pcnt[wv] = __popcll(pmask); s_acnt[wv] = __popcll(amask); }
    __syncthreads();

    int posBase = 0, actBase = 0, np = 0, total = 0;
    #pragma unroll
    for (int wk = 0; wk < 4; ++wk) {
        const int pc = s_pcnt[wk], ac = s_acnt[wk];
        np    += pc;
        total += ac;
        if (wk < wv) { posBase += pc; actBase += ac; }
    }
    const int negBase = (wv << 6) - posBase;      // 64*wv - pos_prefix
    const unsigned long long lt = (1ull << ln) - 1ull;
    const int prank = __popcll(pmask & lt);
    const int arank = __popcll(amask & lt);

    // ---- scatter compacted data ----
    if (pmb) s_pos[posBase + prank]        = yp;
    else     s_neg[negBase + (ln - prank)] = yp;
    if (act) s_act[actBase + arank] = make_float2(a, s);

    // ---- sentinel pads (relu kills them: s=+1 reads d=a-yp, s=-1 reads d=a+yp)
    const int nn   = B_DIM - np;
    const int mx   = (np > nn) ? np : nn;
    const int trip = (mx + 1) >> 1;
    const int lim  = trip << 1;                   // <= 256
    if (tid >= np && tid < lim) s_pos[tid] =  1.0e30f;
    if (tid >= nn && tid < lim) s_neg[tid] = -1.0e30f;
    __syncthreads();

    // ---- compacted inner loop (typically ~62 of 256 threads, ~68 f2 iters) ----
    float acc0 = 0.0f, acc1 = 0.0f;
    if (tid < total) {
        const float2 as   = s_act[tid];
        const float  nsgn = -as.y;
        const float2* lst = (as.y > 0.0f) ? (const float2*)s_pos
                                          : (const float2*)s_neg;
        #pragma unroll 4
        for (int k = 0; k < trip; ++k) {
            const float2 v = lst[k];              // 2-address broadcast: free
            float d0 = fmaxf(fmaf(nsgn, v.x, as.x), 0.0f);
            acc0 = fmaf(d0, d0, acc0);
            float d1 = fmaxf(fmaf(nsgn, v.y, as.x), 0.0f);
            acc1 = fmaf(d1, d1, acc1);
        }
    }

    const float bs = block_sum(acc0 + acc1, tid, red4);
    if (tid == 0) ws[WS_M + c * XBLK + x] = bs;
}

// K3: one block. Thread c<19 folds its class's 32 partials + degenerate logic;
// single-wave shuffle reduce over classes.
__global__ void rocstar_k3(const float* __restrict__ ws,
                           float* __restrict__ out) {
    const int tid = threadIdx.x;
    float r = 0.0f;
    if (tid < C_DIM) {
        float m = 0.0f;
        #pragma unroll
        for (int t = 0; t < XBLK; ++t) m += ws[WS_M + tid * XBLK + t];
        float v = m / 1000.0f;                  // m2/MAX_POS + m3/MAX_NEG
        if (isnan(v)) v = 0.0f;
        const float npos = ws[WS_NPOS + tid];
        r = (npos == 0.0f || npos == (float)B_DIM)
                ? ws[WS_SYP + tid] * 1e-8f      // degenerate: sum(yp)*1e-8
                : v;
    }
    #pragma unroll
    for (int off = 16; off > 0; off >>= 1) r += __shfl_down(r, off, 64);
    if (tid == 0) out[0] = r / (float)C_DIM;    // mean over classes
}

extern "C" void kernel_launch(void* const* d_in, const int* in_sizes, int n_in,
                              void* d_out, int out_size, void* d_ws, size_t ws_size,
                              hipStream_t stream) {
    const float* y_pred     = (const float*)d_in[0];
    const float* y_true     = (const float*)d_in[1];
    const float* epoch_pred = (const float*)d_in[2];
    const float* epoch_true = (const float*)d_in[3];
    const float* gamma      = (const float*)d_in[4];
    const float* rand_pos   = (const float*)d_in[5];
    const float* rand_neg   = (const float*)d_in[6];
    float*       out        = (float*)d_out;
    float*       ws         = (float*)d_ws;

    const dim3 grid(XBLK, C_DIM);   // 32 x 19
    rocstar_k1<<<grid, B_DIM, 0, stream>>>(y_pred, y_true, epoch_true, ws);
    rocstar_k2<<<grid, B_DIM, 0, stream>>>(y_pred, y_true, epoch_pred, epoch_true,
                                           gamma, rand_pos, rand_neg, ws);
    rocstar_k3<<<1, 64, 0, stream>>>(ws, out);
}